// Round 7
// baseline (4767.944 us; speedup 1.0000x reference)
//
#include <hip/hip_runtime.h>

#define T_SEQ  2048
#define DIN    16
#define HH     80
#define BT     16     // batches per block
#define NBLK   32     // 32 * 16 = 512 = BATCH
#define NTHR   640    // 10 waves: 0-4 = L1, 5-9 = L2
#define RS     128    // h-buffer row stride (f16 elements), 16 chunks of 8
#define RSX    64     // x-buffer row stride (8 chunks)

typedef _Float16 h8  __attribute__((ext_vector_type(8)));
typedef _Float16 hv4 __attribute__((ext_vector_type(4)));
typedef float    f4  __attribute__((ext_vector_type(4)));

__device__ __forceinline__ float rcp_fast(float x){ return __builtin_amdgcn_rcpf(x); }
__device__ __forceinline__ float sigm(float x)  { return rcp_fast(1.0f + __expf(-x)); }
__device__ __forceinline__ float tanh_f(float x){ return 1.0f - 2.0f*rcp_fast(1.0f + __expf(2.0f*x)); }

// Anti-remat pin on a whole 128-bit fragment: keeps it a contiguous VGPR quad
// and forbids re-materializing the global load inside the loop (R3 lesson).
#define PINV(v) asm volatile("" : "+v"(v))

// B-fragment: 8 contiguous f32 of weight row n starting at k=koff, cvt to f16.
// Rows are W[n][0..K); koff clamped so we never read past the row (the A side
// is zero-padded there, so the clamped values multiply zero).
__device__ __forceinline__ h8 ldfrag(const float* __restrict__ W, int n, int K, int koff){
    if (koff + 8 > K) koff = K - 8;
    const float4* p = (const float4*)(W + (size_t)n*K + koff);
    const float4 a = p[0], b = p[1];
    h8 r;
    r[0]=(_Float16)a.x; r[1]=(_Float16)a.y; r[2]=(_Float16)a.z; r[3]=(_Float16)a.w;
    r[4]=(_Float16)b.x; r[5]=(_Float16)b.y; r[6]=(_Float16)b.z; r[7]=(_Float16)b.w;
    return r;
}

__device__ __forceinline__ f4 mfma16(h8 a, h8 b, f4 c){
    return __builtin_amdgcn_mfma_f32_16x16x32_f16(a, b, c, 0, 0, 0);
}

// A-fragment read: lane holds A[m=lane&15][k=quad*8+j]; logical chunk c=kt*4+quad,
// XOR-swizzled by (m&7) for bank spread; 16B aligned (chunk granularity).
__device__ __forceinline__ h8 rdA(const _Float16* buf, int m, int c){
    return *(const h8*)(buf + m*RS + (((c) ^ (m & 7)) << 3));
}

__global__
__attribute__((amdgpu_flat_work_group_size(NTHR, NTHR)))
__attribute__((amdgpu_waves_per_eu(3, 3)))   // 10 waves/CU worst-case 3/SIMD -> ~170-reg budget
void lstm2_mfma(
    const float* __restrict__ x,
    const float* __restrict__ W_ih1, const float* __restrict__ W_hh1,
    const float* __restrict__ b_ih1, const float* __restrict__ b_hh1,
    const float* __restrict__ W_ih2, const float* __restrict__ W_hh2,
    const float* __restrict__ b_ih2, const float* __restrict__ b_hh2,
    const float* __restrict__ W_d,   const float* __restrict__ b_d,
    float* __restrict__ out)
{
    __shared__ __align__(16) _Float16 H1[BT*RS];   // layer-1 hidden, f16, swizzled
    __shared__ __align__(16) _Float16 H2[BT*RS];   // layer-2 hidden
    __shared__ __align__(16) _Float16 XB[BT*RSX];  // current x_t, f16, swizzled

    const int t    = threadIdx.x;
    const int lane = t & 63;
    const int wv   = t >> 6;
    const int col  = lane & 15;
    const int quad = lane >> 4;
    const bool L1  = (wv < 5);
    const int  w   = L1 ? wv : wv - 5;
    const int  ucb = 16 * w;              // this wave's unit-column base
    const int  b0  = blockIdx.x * BT;

    // ---- zero LDS (pad chunks must stay zero forever) ----
    for (int i = t; i < BT*RS;  i += NTHR){ H1[i] = (_Float16)0.f; H2[i] = (_Float16)0.f; }
    for (int i = t; i < BT*RSX; i += NTHR){ XB[i] = (_Float16)0.f; }

    // ---- persistent B-fragments (registers), 4 gates x 6 slots ----
    // L1: PA=W_hh1(K=80) slots0-2, PB=W_ih1(K=16) slot3 (slots4,5 dead)
    // L2: PA=W_ih2(K=80) slots0-2, PB=W_hh2(K=80) slots3-5
    const float* PA = L1 ? W_hh1 : W_ih2;  const int KA = HH;
    const float* PB = L1 ? W_ih1 : W_hh2;  const int KB = L1 ? DIN : HH;
    const float* Pb1 = L1 ? b_ih1 : b_ih2;
    const float* Pb2 = L1 ? b_hh1 : b_hh2;

    h8 B00,B01,B02,B03,B04,B05, B10,B11,B12,B13,B14,B15,
       B20,B21,B22,B23,B24,B25, B30,B31,B32,B33,B34,B35;
#define LOADG(g) { const int n = (g)*HH + ucb + col; \
    B##g##0 = ldfrag(PA, n, KA,      quad*8); \
    B##g##1 = ldfrag(PA, n, KA, 32 + quad*8); \
    B##g##2 = ldfrag(PA, n, KA, 64 + quad*8); \
    B##g##3 = ldfrag(PB, n, KB,      quad*8); \
    B##g##4 = ldfrag(PB, n, KB, 32 + quad*8); \
    B##g##5 = ldfrag(PB, n, KB, 64 + quad*8); }
    LOADG(0) LOADG(1) LOADG(2) LOADG(3)
#undef LOADG
    PINV(B00); PINV(B01); PINV(B02); PINV(B03);
    PINV(B10); PINV(B11); PINV(B12); PINV(B13);
    PINV(B20); PINV(B21); PINV(B22); PINV(B23);
    PINV(B30); PINV(B31); PINV(B32); PINV(B33);
    if (!L1){ PINV(B04); PINV(B05); PINV(B14); PINV(B15);
              PINV(B24); PINV(B25); PINV(B34); PINV(B35); }

    // ---- per-lane biases (one unit column, 4 gates) ----
    float bb0 = Pb1[0*HH+ucb+col] + Pb2[0*HH+ucb+col];
    float bb1 = Pb1[1*HH+ucb+col] + Pb2[1*HH+ucb+col];
    float bb2 = Pb1[2*HH+ucb+col] + Pb2[2*HH+ucb+col];
    float bb3 = Pb1[3*HH+ucb+col] + Pb2[3*HH+ucb+col];
    asm volatile("" : "+v"(bb0), "+v"(bb1), "+v"(bb2), "+v"(bb3));

    f4 cst = {0.f, 0.f, 0.f, 0.f};   // cell state: 4 batches (quad*4+r) x 1 unit

    __syncthreads();
    // ---- pre-stage x(0) ----
    if (wv == 0){
        const int b = lane >> 2, c4 = (lane & 3) * 4;
        const float4 v = *(const float4*)(x + ((size_t)(b0+b)*T_SEQ + 0)*DIN + c4);
        hv4 hx; hx[0]=(_Float16)v.x; hx[1]=(_Float16)v.y; hx[2]=(_Float16)v.z; hx[3]=(_Float16)v.w;
        *(hv4*)(XB + b*RSX + (((c4>>3) ^ (b&7)) << 3) + (c4&7)) = hx;
    }
    __syncthreads();

    // ---- recurrent loop: iter j computes h1(j) [L1] and h2(j-1) [L2] ----
    #pragma unroll 1
    for (int j = 0; j <= T_SEQ; ++j){
        const bool actL1 = L1 && (j < T_SEQ);
        const bool actL2 = (!L1) && (j >= 1);

        // phase A: read A-fragments (values carried in regs across the barrier)
        h8 a0, a1, a2, ax, d0, d1, d2;
        if (actL1 | actL2){
            a0 = rdA(H1, col,     quad);
            a1 = rdA(H1, col, 4 + quad);
            a2 = rdA(H1, col, 8 + quad);
        }
        if (actL1){
            ax = *(const h8*)(XB + col*RSX + ((quad ^ (col & 7)) << 3));
        }
        if (actL2){
            d0 = rdA(H2, col,     quad);
            d1 = rdA(H2, col, 4 + quad);
            d2 = rdA(H2, col, 8 + quad);
        }
        // issue next-x global load early (consumed in phase B)
        float4 xg;
        const bool doStage = (wv == 0) && (j + 1 < T_SEQ);
        if (doStage)
            xg = *(const float4*)(x + ((size_t)(b0 + (lane>>2))*T_SEQ + (j+1))*DIN + (lane&3)*4);

        __syncthreads();

        // phase B: MFMA + in-register gate epilogue + h write
        if (actL1 | actL2){
            f4 Ci = {bb0,bb0,bb0,bb0}, Cf = {bb1,bb1,bb1,bb1},
               Cg = {bb2,bb2,bb2,bb2}, Co = {bb3,bb3,bb3,bb3};
            Ci = mfma16(a0,B00,Ci); Cf = mfma16(a0,B10,Cf); Cg = mfma16(a0,B20,Cg); Co = mfma16(a0,B30,Co);
            Ci = mfma16(a1,B01,Ci); Cf = mfma16(a1,B11,Cf); Cg = mfma16(a1,B21,Cg); Co = mfma16(a1,B31,Co);
            Ci = mfma16(a2,B02,Ci); Cf = mfma16(a2,B12,Cf); Cg = mfma16(a2,B22,Cg); Co = mfma16(a2,B32,Co);
            if (actL1){
                Ci = mfma16(ax,B03,Ci); Cf = mfma16(ax,B13,Cf); Cg = mfma16(ax,B23,Cg); Co = mfma16(ax,B33,Co);
            } else {
                Ci = mfma16(d0,B03,Ci); Cf = mfma16(d0,B13,Cf); Cg = mfma16(d0,B23,Cg); Co = mfma16(d0,B33,Co);
                Ci = mfma16(d1,B04,Ci); Cf = mfma16(d1,B14,Cf); Cg = mfma16(d1,B24,Cg); Co = mfma16(d1,B34,Co);
                Ci = mfma16(d2,B05,Ci); Cf = mfma16(d2,B15,Cf); Cg = mfma16(d2,B25,Cg); Co = mfma16(d2,B35,Co);
            }
            _Float16* HD = L1 ? H1 : H2;
            const int u = ucb + col;
            #pragma unroll
            for (int r = 0; r < 4; ++r){
                const float iv = sigm(Ci[r]), fv = sigm(Cf[r]),
                            gv = tanh_f(Cg[r]), ov = sigm(Co[r]);
                cst[r] = fv*cst[r] + iv*gv;
                const float hval = ov * tanh_f(cst[r]);
                const int m = quad*4 + r;
                HD[m*RS + (((u>>3) ^ (m&7)) << 3) + (u&7)] = (_Float16)hval;
            }
        }
        if (doStage){
            const int b = lane >> 2, c4 = (lane & 3) * 4;
            hv4 hx; hx[0]=(_Float16)xg.x; hx[1]=(_Float16)xg.y; hx[2]=(_Float16)xg.z; hx[3]=(_Float16)xg.w;
            *(hv4*)(XB + b*RSX + (((c4>>3) ^ (b&7)) << 3) + (c4&7)) = hx;
        }
        __syncthreads();
    }

    // ---- dense head: out[b] = h2(T-1)[b] . W_d + b_d ----
    if (t < BT){
        float acc = b_d[0];
        #pragma unroll
        for (int u = 0; u < HH; ++u)
            acc += W_d[u] * (float)H2[t*RS + (((u>>3) ^ (t&7)) << 3) + (u&7)];
        out[b0 + t] = acc;
    }
}

extern "C" void kernel_launch(void* const* d_in, const int* in_sizes, int n_in,
                              void* d_out, int out_size, void* d_ws, size_t ws_size,
                              hipStream_t stream) {
    const float* x     = (const float*)d_in[0];
    const float* W_ih1 = (const float*)d_in[1];
    const float* W_hh1 = (const float*)d_in[2];
    const float* b_ih1 = (const float*)d_in[3];
    const float* b_hh1 = (const float*)d_in[4];
    const float* W_ih2 = (const float*)d_in[5];
    const float* W_hh2 = (const float*)d_in[6];
    const float* b_ih2 = (const float*)d_in[7];
    const float* b_hh2 = (const float*)d_in[8];
    const float* W_d   = (const float*)d_in[9];
    const float* b_d   = (const float*)d_in[10];

    lstm2_mfma<<<NBLK, NTHR, 0, stream>>>(x, W_ih1, W_hh1, b_ih1, b_hh1,
                                          W_ih2, W_hh2, b_ih2, b_hh2,
                                          W_d, b_d, (float*)d_out);
}

// Round 9
// 2999.530 us; speedup vs baseline: 1.5896x; 1.5896x over previous
//
#include <hip/hip_runtime.h>

#define T_SEQ 2048
#define DIN   16
#define HH    80
#define NTHR  512
#define NBLK  512          // BT = 1
#define HS    96           // f16 stride per h parity buffer: [0,40) half0, [48,88) half1

typedef _Float16 h2v __attribute__((ext_vector_type(2)));

__device__ __forceinline__ float rcp_fast(float x){ return __builtin_amdgcn_rcpf(x); }
__device__ __forceinline__ float sigm(float x)  { return rcp_fast(1.0f + __expf(-x)); }
__device__ __forceinline__ float tanh_f(float x){ return 1.0f - 2.0f*rcp_fast(1.0f + __expf(2.0f*x)); }

// v_dot2_f32_f16 (R6-proven)
static __device__ __forceinline__ float fdot2f(float w, float h, float acc) {
    return __builtin_amdgcn_fdot2(__builtin_bit_cast(h2v, w), __builtin_bit_cast(h2v, h), acc, false);
}
static __device__ __forceinline__ float pk2(float a, float b) {
    h2v v; v.x = (_Float16)a; v.y = (_Float16)b;
    return __builtin_bit_cast(float, v);
}
static __device__ __forceinline__ float4 pkf4(float4 a, float4 b){
    return make_float4(pk2(a.x,a.y), pk2(a.z,a.w), pk2(b.x,b.y), pk2(b.z,b.w));
}
// DPP cross-lane adds (VALU pipe, no LDS): lane^1 and lane^2 within quads
static __device__ __forceinline__ float qswap1(float v){
    int r = __builtin_amdgcn_update_dpp(0, __builtin_bit_cast(int, v), 0xB1, 0xF, 0xF, true); // quad_perm [1,0,3,2]
    return __builtin_bit_cast(float, r);
}
static __device__ __forceinline__ float qswap2(float v){
    int r = __builtin_amdgcn_update_dpp(0, __builtin_bit_cast(int, v), 0x4E, 0xF, 0xF, true); // quad_perm [2,3,0,1]
    return __builtin_bit_cast(float, r);
}

// Anti-remat pin, component-wise (R5/R6-proven form; whole-struct "+v" fails to compile)
#define PIN4(v) asm volatile("" : "+v"(v.x), "+v"(v.y), "+v"(v.z), "+v"(v.w))

// 40 consecutive f32 -> 5 float4 of f16-pairs
#define LOADW5(W, ptr) { const float4* P = (const float4*)(ptr); \
    W##0 = pkf4(P[0],P[1]); W##1 = pkf4(P[2],P[3]); W##2 = pkf4(P[4],P[5]); \
    W##3 = pkf4(P[6],P[7]); W##4 = pkf4(P[8],P[9]); }

// 4 dot2 = 8 MACs: one 16B chunk of weights vs h
#define DG(acc, Wq, Hq) { acc = fdot2f(Wq.x, Hq.x, acc); acc = fdot2f(Wq.y, Hq.y, acc); \
                          acc = fdot2f(Wq.z, Hq.z, acc); acc = fdot2f(Wq.w, Hq.w, acc); }
// full 40-element slice for one gate
#define G5(acc, W) { DG(acc, W##0, h0) DG(acc, W##1, h1) DG(acc, W##2, h2) DG(acc, W##3, h3) DG(acc, W##4, h4) }

__global__
__attribute__((amdgpu_flat_work_group_size(NTHR, NTHR)))
__attribute__((amdgpu_waves_per_eu(4, 4)))   // 128-reg cap -> 2 blocks/CU (R6-proven shape)
void lstm2_fused(
    const float* __restrict__ x,
    const float* __restrict__ W_ih1, const float* __restrict__ W_hh1,
    const float* __restrict__ b_ih1, const float* __restrict__ b_hh1,
    const float* __restrict__ W_ih2, const float* __restrict__ W_hh2,
    const float* __restrict__ b_ih2, const float* __restrict__ b_hh2,
    const float* __restrict__ W_d,   const float* __restrict__ b_d,
    float* __restrict__ out)
{
    __shared__ __align__(16) _Float16 H1[2*HS];   // layer-1 hidden, parity-double-buffered
    __shared__ __align__(16) _Float16 H2[2*HS];   // layer-2 hidden
    __shared__ __align__(16) _Float16 XB[2*16];   // x_t, f16, parity-double-buffered

    const int t  = threadIdx.x;
    const int b0 = blockIdx.x;

    // roles: [0,320) L2 (unit=t>>2, K-quarter=t&3); [320,480) L1 (unit=(t-320)>>1, half=t&1);
    //        [480,496) x stagers; rest idle. Waves 0-4 pure L2, 5-6 pure L1, 7 mixed.
    const bool isL2  = (t < 320);
    const bool isL1  = (t >= 320) && (t < 480);
    const bool isStg = (t >= 480) && (t < 496);

    // ---- persistent packed-f16 weights: 4 gates x 40-elem slice = 20 float4 ----
    float4 WI0{},WI1{},WI2{},WI3{},WI4{}, WF0{},WF1{},WF2{},WF3{},WF4{},
           WG0{},WG1{},WG2{},WG3{},WG4{}, WO0{},WO1{},WO2{},WO3{},WO4{};
    float4 XI{},XF{},XG{},XO{};           // L1 only: x-projection slice (8 of 16)
    float bi = 0.f, bf = 0.f, bg = 0.f, bo = 0.f;

    if (isL2) {
        const int u = t >> 2, q = t & 3;
        // q0,q1: W_ih2 halves over h1 ; q2,q3: W_hh2 halves over h2
        const float* src = (q < 2) ? W_ih2 : W_hh2;
        const int ko = 40 * (q & 1);
        LOADW5(WI, src + (size_t)(0*HH + u)*HH + ko);
        LOADW5(WF, src + (size_t)(1*HH + u)*HH + ko);
        LOADW5(WG, src + (size_t)(2*HH + u)*HH + ko);
        LOADW5(WO, src + (size_t)(3*HH + u)*HH + ko);
        bi = b_ih2[0*HH+u] + b_hh2[0*HH+u];
        bf = b_ih2[1*HH+u] + b_hh2[1*HH+u];
        bg = b_ih2[2*HH+u] + b_hh2[2*HH+u];
        bo = b_ih2[3*HH+u] + b_hh2[3*HH+u];
    } else if (isL1) {
        const int u = (t - 320) >> 1, half = t & 1;
        const int ko = 40 * half;
        LOADW5(WI, W_hh1 + (size_t)(0*HH + u)*HH + ko);
        LOADW5(WF, W_hh1 + (size_t)(1*HH + u)*HH + ko);
        LOADW5(WG, W_hh1 + (size_t)(2*HH + u)*HH + ko);
        LOADW5(WO, W_hh1 + (size_t)(3*HH + u)*HH + ko);
        const float4* Q0 = (const float4*)(W_ih1 + (size_t)(0*HH + u)*DIN + 8*half);
        const float4* Q1 = (const float4*)(W_ih1 + (size_t)(1*HH + u)*DIN + 8*half);
        const float4* Q2 = (const float4*)(W_ih1 + (size_t)(2*HH + u)*DIN + 8*half);
        const float4* Q3 = (const float4*)(W_ih1 + (size_t)(3*HH + u)*DIN + 8*half);
        XI = pkf4(Q0[0], Q0[1]); XF = pkf4(Q1[0], Q1[1]);
        XG = pkf4(Q2[0], Q2[1]); XO = pkf4(Q3[0], Q3[1]);
        bi = b_ih1[0*HH+u] + b_hh1[0*HH+u];
        bf = b_ih1[1*HH+u] + b_hh1[1*HH+u];
        bg = b_ih1[2*HH+u] + b_hh1[2*HH+u];
        bo = b_ih1[3*HH+u] + b_hh1[3*HH+u];
    }
    PIN4(WI0); PIN4(WI1); PIN4(WI2); PIN4(WI3); PIN4(WI4);
    PIN4(WF0); PIN4(WF1); PIN4(WF2); PIN4(WF3); PIN4(WF4);
    PIN4(WG0); PIN4(WG1); PIN4(WG2); PIN4(WG3); PIN4(WG4);
    PIN4(WO0); PIN4(WO1); PIN4(WO2); PIN4(WO3); PIN4(WO4);
    PIN4(XI);  PIN4(XF);  PIN4(XG);  PIN4(XO);
    asm volatile("" : "+v"(bi), "+v"(bf), "+v"(bg), "+v"(bo));

    // ---- zero h buffers (both parities), pre-stage x(0) ----
    for (int i = t; i < 2*HS; i += NTHR) { H1[i] = (_Float16)0.f; H2[i] = (_Float16)0.f; }
    if (isStg) {
        const int s = t - 480;
        XB[s] = (_Float16)x[((size_t)b0 * T_SEQ + 0) * DIN + s];
    }
    __syncthreads();

    float c_reg = 0.0f;

    // iter k: L1 computes h1(k) [reads h1(k-1), x(k)]; L2 computes h2(k-1)
    // [reads h1(k-1), h2(k-2)]. Reads from parity pb=k&1, writes to nb=pb^1.
    #pragma unroll 1
    for (int k = 0; k <= T_SEQ; ++k) {
        const int pb = k & 1, nb = pb ^ 1;
        if (isL2) {
            if (k >= 1) {
                const int u = t >> 2, q = t & 3;
                const _Float16* hb = ((q < 2) ? H1 : H2) + HS*pb + 48*(q & 1);
                const float4 h0 = ((const float4*)hb)[0], h1 = ((const float4*)hb)[1],
                             h2 = ((const float4*)hb)[2], h3 = ((const float4*)hb)[3],
                             h4 = ((const float4*)hb)[4];
                float ai = 0.f, af = 0.f, ag = 0.f, ao = 0.f;
                G5(ai, WI) G5(af, WF) G5(ag, WG) G5(ao, WO)
                ai += qswap1(ai); af += qswap1(af); ag += qswap1(ag); ao += qswap1(ao);
                ai += qswap2(ai); af += qswap2(af); ag += qswap2(ag); ao += qswap2(ao);
                const float iv = sigm(ai + bi), fv = sigm(af + bf),
                            gv = tanh_f(ag + bg), ov = sigm(ao + bo);
                c_reg = fv*c_reg + iv*gv;
                const float hval = ov * tanh_f(c_reg);
                if (q == 0) H2[HS*nb + (u < 40 ? u : u + 8)] = (_Float16)hval;
            }
        } else if (isL1) {
            if (k < T_SEQ) {
                const int u = (t - 320) >> 1, half = t & 1;
                const _Float16* hb = H1 + HS*pb + 48*half;
                const float4 h0 = ((const float4*)hb)[0], h1 = ((const float4*)hb)[1],
                             h2 = ((const float4*)hb)[2], h3 = ((const float4*)hb)[3],
                             h4 = ((const float4*)hb)[4];
                const float4 xv = ((const float4*)(XB + 16*pb))[half];
                float ai = 0.f, af = 0.f, ag = 0.f, ao = 0.f;
                G5(ai, WI) G5(af, WF) G5(ag, WG) G5(ao, WO)
                DG(ai, XI, xv) DG(af, XF, xv) DG(ag, XG, xv) DG(ao, XO, xv)
                ai += qswap1(ai); af += qswap1(af); ag += qswap1(ag); ao += qswap1(ao);
                const float iv = sigm(ai + bi), fv = sigm(af + bf),
                            gv = tanh_f(ag + bg), ov = sigm(ao + bo);
                c_reg = fv*c_reg + iv*gv;
                const float hval = ov * tanh_f(c_reg);
                if (half == 0) H1[HS*nb + (u < 40 ? u : u + 8)] = (_Float16)hval;
            }
        } else if (isStg) {
            if (k + 1 < T_SEQ) {
                const int s = t - 480;
                const float xg = x[((size_t)b0 * T_SEQ + (k + 1)) * DIN + s];
                XB[16*nb + s] = (_Float16)xg;
            }
        }
        __syncthreads();
    }

    // ---- dense head: out[b0] = h2(T-1) . W_d + b_d ----
    if (t == 0) {
        const _Float16* hf = H2 + HS * ((T_SEQ + 1) & 1);
        float acc = b_d[0];
        #pragma unroll
        for (int u = 0; u < HH; ++u)
            acc += W_d[u] * (float)hf[u < 40 ? u : u + 8];
        out[b0] = acc;
    }
}

extern "C" void kernel_launch(void* const* d_in, const int* in_sizes, int n_in,
                              void* d_out, int out_size, void* d_ws, size_t ws_size,
                              hipStream_t stream) {
    const float* x     = (const float*)d_in[0];
    const float* W_ih1 = (const float*)d_in[1];
    const float* W_hh1 = (const float*)d_in[2];
    const float* b_ih1 = (const float*)d_in[3];
    const float* b_hh1 = (const float*)d_in[4];
    const float* W_ih2 = (const float*)d_in[5];
    const float* W_hh2 = (const float*)d_in[6];
    const float* b_ih2 = (const float*)d_in[7];
    const float* b_hh2 = (const float*)d_in[8];
    const float* W_d   = (const float*)d_in[9];
    const float* b_d   = (const float*)d_in[10];

    lstm2_fused<<<NBLK, NTHR, 0, stream>>>(x, W_ih1, W_hh1, b_ih1, b_hh1,
                                           W_ih2, W_hh2, b_ih2, b_hh2,
                                           W_d, b_d, (float*)d_out);
}

// Round 10
// 2575.142 us; speedup vs baseline: 1.8515x; 1.1648x over previous
//
#include <hip/hip_runtime.h>

#define T_SEQ 2048
#define DIN   16
#define HH    80
#define NTHR  512
#define NBLK  256
#define BT    2

typedef _Float16 h2v __attribute__((ext_vector_type(2)));

__device__ __forceinline__ float rcp_fast(float x){ return __builtin_amdgcn_rcpf(x); }
__device__ __forceinline__ float sigm(float x)  { return rcp_fast(1.0f + __expf(-x)); }
__device__ __forceinline__ float tanh_f(float x){ return 1.0f - 2.0f*rcp_fast(1.0f + __expf(2.0f*x)); }

static __device__ __forceinline__ float fdot2f(float w, float h, float acc) {
    return __builtin_amdgcn_fdot2(__builtin_bit_cast(h2v, w), __builtin_bit_cast(h2v, h), acc, false);
}
static __device__ __forceinline__ float pk2(float a, float b) {
    h2v v; v.x = (_Float16)a; v.y = (_Float16)b;
    return __builtin_bit_cast(float, v);
}
static __device__ __forceinline__ float4 pkf4(float4 a, float4 b){
    return make_float4(pk2(a.x,a.y), pk2(a.z,a.w), pk2(b.x,b.y), pk2(b.z,b.w));
}
static __device__ __forceinline__ float qswap1(float v){
    int r = __builtin_amdgcn_update_dpp(0, __builtin_bit_cast(int, v), 0xB1, 0xF, 0xF, true);
    return __builtin_bit_cast(float, r);
}
static __device__ __forceinline__ float qswap2(float v){
    int r = __builtin_amdgcn_update_dpp(0, __builtin_bit_cast(int, v), 0x4E, 0xF, 0xF, true);
    return __builtin_bit_cast(float, r);
}

#define PIN4(v) asm volatile("" : "+v"(v.x), "+v"(v.y), "+v"(v.z), "+v"(v.w))
#define PK(P, c) pkf4((P)[2*(c)], (P)[2*(c)+1])
#define DG4(acc, Wq, Hq) { acc = fdot2f(Wq.x, Hq.x, acc); acc = fdot2f(Wq.y, Hq.y, acc); \
                           acc = fdot2f(Wq.z, Hq.z, acc); acc = fdot2f(Wq.w, Hq.w, acc); }
#define PIN_ALL  PIN4(WA0);PIN4(WA1);PIN4(WA2);PIN4(WA3);PIN4(WA4);PIN4(WA5); \
                 PIN4(WB0);PIN4(WB1);PIN4(WB2);PIN4(WB3);PIN4(WB4);PIN4(WB5); \
                 PIN4(WC0);PIN4(WC1);PIN4(WC2);PIN4(WC3);PIN4(WC4);PIN4(WC5); \
                 PIN4(WD0);PIN4(WD1);PIN4(WD2);PIN4(WD3);PIN4(WD4);PIN4(WD5); \
                 asm volatile("" : "+v"(bi), "+v"(bf), "+v"(bg), "+v"(bo))

__global__
__attribute__((amdgpu_flat_work_group_size(NTHR, NTHR)))
__attribute__((amdgpu_waves_per_eu(2, 2)))   // 256-reg budget: weights + working fit with slack
void lstm2_fused(
    const float* __restrict__ x,
    const float* __restrict__ W_ih1, const float* __restrict__ W_hh1,
    const float* __restrict__ b_ih1, const float* __restrict__ b_hh1,
    const float* __restrict__ W_ih2, const float* __restrict__ W_hh2,
    const float* __restrict__ b_ih2, const float* __restrict__ b_hh2,
    const float* __restrict__ W_d,   const float* __restrict__ b_d,
    float* __restrict__ out)
{
    __shared__ __align__(16) _Float16 H1[BT][2][HH];  // [batch][parity][unit]
    __shared__ __align__(16) _Float16 H2[BT][2][HH];
    __shared__ __align__(16) _Float16 XB[BT][2][DIN];

    const int t  = threadIdx.x;
    const int b0 = blockIdx.x * BT;

    // roles: waves 0-4 = L2 (u=t>>2, K-quarter q=t&3 over [h1|h2]);
    //        t in [320,480) = L1 (u=(t-320)>>1, K-half s=t&1 over [h1|x]);
    //        t in [480,512) = x stagers.
    const bool isL2  = (t < 320);
    const bool isL1  = (t >= 320) && (t < 480);

    const int uL2 = t >> 2,        qL2 = t & 3;
    const int uL1 = (t - 320) >> 1, sL1 = t & 1;
    const int ko  = isL2 ? 40*(qL2 & 1) : 40*sL1;    // element offset within the h vector

    // ---- persistent packed-f16 weights: 4 gates x up-to-6 chunks ----
    float4 WA0{},WA1{},WA2{},WA3{},WA4{},WA5{}, WB0{},WB1{},WB2{},WB3{},WB4{},WB5{},
           WC0{},WC1{},WC2{},WC3{},WC4{},WC5{}, WD0{},WD1{},WD2{},WD3{},WD4{},WD5{};
    float bi = 0.f, bf = 0.f, bg = 0.f, bo = 0.f;

    if (isL2) {
        const float* src = (qL2 < 2) ? W_ih2 : W_hh2;   // q0,q1: over h1 ; q2,q3: over h2
        const float4* P0 = (const float4*)(src + (size_t)(0*HH + uL2)*HH + ko);
        const float4* P1 = (const float4*)(src + (size_t)(1*HH + uL2)*HH + ko);
        const float4* P2 = (const float4*)(src + (size_t)(2*HH + uL2)*HH + ko);
        const float4* P3 = (const float4*)(src + (size_t)(3*HH + uL2)*HH + ko);
        WA0=PK(P0,0); WA1=PK(P0,1); WA2=PK(P0,2); WA3=PK(P0,3); WA4=PK(P0,4);
        WB0=PK(P1,0); WB1=PK(P1,1); WB2=PK(P1,2); WB3=PK(P1,3); WB4=PK(P1,4);
        WC0=PK(P2,0); WC1=PK(P2,1); WC2=PK(P2,2); WC3=PK(P2,3); WC4=PK(P2,4);
        WD0=PK(P3,0); WD1=PK(P3,1); WD2=PK(P3,2); WD3=PK(P3,3); WD4=PK(P3,4);
        bi = b_ih2[0*HH+uL2] + b_hh2[0*HH+uL2];
        bf = b_ih2[1*HH+uL2] + b_hh2[1*HH+uL2];
        bg = b_ih2[2*HH+uL2] + b_hh2[2*HH+uL2];
        bo = b_ih2[3*HH+uL2] + b_hh2[3*HH+uL2];
    } else if (isL1) {
        const float4* P0 = (const float4*)(W_hh1 + (size_t)(0*HH + uL1)*HH + ko);
        const float4* P1 = (const float4*)(W_hh1 + (size_t)(1*HH + uL1)*HH + ko);
        const float4* P2 = (const float4*)(W_hh1 + (size_t)(2*HH + uL1)*HH + ko);
        const float4* P3 = (const float4*)(W_hh1 + (size_t)(3*HH + uL1)*HH + ko);
        WA0=PK(P0,0); WA1=PK(P0,1); WA2=PK(P0,2); WA3=PK(P0,3); WA4=PK(P0,4);
        WB0=PK(P1,0); WB1=PK(P1,1); WB2=PK(P1,2); WB3=PK(P1,3); WB4=PK(P1,4);
        WC0=PK(P2,0); WC1=PK(P2,1); WC2=PK(P2,2); WC3=PK(P2,3); WC4=PK(P2,4);
        WD0=PK(P3,0); WD1=PK(P3,1); WD2=PK(P3,2); WD3=PK(P3,3); WD4=PK(P3,4);
        const float4* X0 = (const float4*)(W_ih1 + (size_t)(0*HH + uL1)*DIN + 8*sL1);
        const float4* X1 = (const float4*)(W_ih1 + (size_t)(1*HH + uL1)*DIN + 8*sL1);
        const float4* X2 = (const float4*)(W_ih1 + (size_t)(2*HH + uL1)*DIN + 8*sL1);
        const float4* X3 = (const float4*)(W_ih1 + (size_t)(3*HH + uL1)*DIN + 8*sL1);
        WA5 = pkf4(X0[0], X0[1]); WB5 = pkf4(X1[0], X1[1]);
        WC5 = pkf4(X2[0], X2[1]); WD5 = pkf4(X3[0], X3[1]);
        bi = b_ih1[0*HH+uL1] + b_hh1[0*HH+uL1];
        bf = b_ih1[1*HH+uL1] + b_hh1[1*HH+uL1];
        bg = b_ih1[2*HH+uL1] + b_hh1[2*HH+uL1];
        bo = b_ih1[3*HH+uL1] + b_hh1[3*HH+uL1];
    }

    // ---- zero h states (both parities), pre-stage x(0) ----
    if (t < BT*2*HH) { ((_Float16*)H1)[t] = (_Float16)0.f; ((_Float16*)H2)[t] = (_Float16)0.f; }
    if (t >= 480) {
        const int b = (t - 480) >> 4, s16 = t & 15;
        XB[b][0][s16] = (_Float16)x[((size_t)(b0+b)*T_SEQ + 0)*DIN + s16];
    }
    __syncthreads();

    float cA = 0.f, cB = 0.f;   // cell state for batch 0 / batch 1 (held in epilogue lanes)

    // iter k: L1 computes h1(k) [reads h1(k-1), x(k)]; L2 computes h2(k-1)
    // [reads h1(k-1), h2(k-2)]. Reads parity pb, writes nb.
    #pragma unroll 1
    for (int k = 0; k <= T_SEQ; ++k) {
        const int pb = k & 1, nb = pb ^ 1;
        PIN_ALL;   // in-loop pin: forces VGPR residency every iteration (anti-AGPR-stash)

        if (isL2) {
            if (k >= 1) {
                #pragma unroll
                for (int b = 0; b < BT; ++b) {
                    const _Float16* hb = ((qL2 < 2) ? &H1[b][pb][0] : &H2[b][pb][0]) + ko;
                    const float4 h0 = ((const float4*)hb)[0], h1 = ((const float4*)hb)[1],
                                 h2 = ((const float4*)hb)[2], h3 = ((const float4*)hb)[3],
                                 h4 = ((const float4*)hb)[4];
                    float ai=0.f, af=0.f, ag=0.f, ao=0.f;
                    DG4(ai,WA0,h0) DG4(ai,WA1,h1) DG4(ai,WA2,h2) DG4(ai,WA3,h3) DG4(ai,WA4,h4)
                    DG4(af,WB0,h0) DG4(af,WB1,h1) DG4(af,WB2,h2) DG4(af,WB3,h3) DG4(af,WB4,h4)
                    DG4(ag,WC0,h0) DG4(ag,WC1,h1) DG4(ag,WC2,h2) DG4(ag,WC3,h3) DG4(ag,WC4,h4)
                    DG4(ao,WD0,h0) DG4(ao,WD1,h1) DG4(ao,WD2,h2) DG4(ao,WD3,h3) DG4(ao,WD4,h4)
                    ai += qswap1(ai); af += qswap1(af); ag += qswap1(ag); ao += qswap1(ao);
                    ai += qswap2(ai); af += qswap2(af); ag += qswap2(ag); ao += qswap2(ao);
                    if (qL2 == 0) {            // masked epilogue: trans issue once per wave
                        float& cs = b ? cB : cA;
                        const float iv = sigm(ai+bi), fv = sigm(af+bf),
                                    gv = tanh_f(ag+bg), ov = sigm(ao+bo);
                        cs = fv*cs + iv*gv;
                        H2[b][nb][uL2] = (_Float16)(ov * tanh_f(cs));
                    }
                }
            }
        } else if (isL1) {
            if (k < T_SEQ) {
                #pragma unroll
                for (int b = 0; b < BT; ++b) {
                    const _Float16* hb = &H1[b][pb][0] + ko;
                    const float4 h0 = ((const float4*)hb)[0], h1 = ((const float4*)hb)[1],
                                 h2 = ((const float4*)hb)[2], h3 = ((const float4*)hb)[3],
                                 h4 = ((const float4*)hb)[4];
                    const float4 xv = *(const float4*)(&XB[b][pb][0] + 8*sL1);
                    float ai=0.f, af=0.f, ag=0.f, ao=0.f;
                    DG4(ai,WA0,h0) DG4(ai,WA1,h1) DG4(ai,WA2,h2) DG4(ai,WA3,h3) DG4(ai,WA4,h4) DG4(ai,WA5,xv)
                    DG4(af,WB0,h0) DG4(af,WB1,h1) DG4(af,WB2,h2) DG4(af,WB3,h3) DG4(af,WB4,h4) DG4(af,WB5,xv)
                    DG4(ag,WC0,h0) DG4(ag,WC1,h1) DG4(ag,WC2,h2) DG4(ag,WC3,h3) DG4(ag,WC4,h4) DG4(ag,WC5,xv)
                    DG4(ao,WD0,h0) DG4(ao,WD1,h1) DG4(ao,WD2,h2) DG4(ao,WD3,h3) DG4(ao,WD4,h4) DG4(ao,WD5,xv)
                    ai += qswap1(ai); af += qswap1(af); ag += qswap1(ag); ao += qswap1(ao);
                    if (sL1 == 0) {
                        float& cs = b ? cB : cA;
                        const float iv = sigm(ai+bi), fv = sigm(af+bf),
                                    gv = tanh_f(ag+bg), ov = sigm(ao+bo);
                        cs = fv*cs + iv*gv;
                        H1[b][nb][uL1] = (_Float16)(ov * tanh_f(cs));
                    }
                }
            }
        } else {
            if (k + 1 < T_SEQ) {
                const int b = (t - 480) >> 4, s16 = t & 15;
                XB[b][nb][s16] = (_Float16)x[((size_t)(b0+b)*T_SEQ + (k+1))*DIN + s16];
            }
        }
        __syncthreads();
    }

    // ---- dense head: out[b] = h2(T-1) . W_d + b_d ; final h2 in parity 1 (T even) ----
    if (t < BT) {
        float acc = b_d[0];
        #pragma unroll
        for (int u = 0; u < HH; ++u) acc += W_d[u] * (float)H2[t][1][u];
        out[b0 + t] = acc;
    }
}

extern "C" void kernel_launch(void* const* d_in, const int* in_sizes, int n_in,
                              void* d_out, int out_size, void* d_ws, size_t ws_size,
                              hipStream_t stream) {
    const float* x     = (const float*)d_in[0];
    const float* W_ih1 = (const float*)d_in[1];
    const float* W_hh1 = (const float*)d_in[2];
    const float* b_ih1 = (const float*)d_in[3];
    const float* b_hh1 = (const float*)d_in[4];
    const float* W_ih2 = (const float*)d_in[5];
    const float* W_hh2 = (const float*)d_in[6];
    const float* b_ih2 = (const float*)d_in[7];
    const float* b_hh2 = (const float*)d_in[8];
    const float* W_d   = (const float*)d_in[9];
    const float* b_d   = (const float*)d_in[10];

    lstm2_fused<<<NBLK, NTHR, 0, stream>>>(x, W_ih1, W_hh1, b_ih1, b_hh1,
                                           W_ih2, W_hh2, b_ih2, b_hh2,
                                           W_d, b_d, (float*)d_out);
}